// Round 2
// baseline (137.107 us; speedup 1.0000x reference)
//
#include <hip/hip_runtime.h>

#define N_CONS   4000
#define N_VARS   8000
#define N_EDGES  100000
#define N_TOTAL  12000   // N_CONS + N_VARS
#define HID      16

// ---------------- workspace layout (bytes), total 3,684,000 ----------------
// [0        , 2000000) bitmap  4000*4000 bits (both edge rows are in [0,4000))
// [2000000  , 2016000) deg_c   4000 * int
// [2016000  , 2048000) deg_v   8000 * int   (only [0,4000) reachable; rest stay 0)
// [2048000  , 2816000) y       12000*16 f32 (reused for both aggregations)
// [2816000  , 3584000) x       12000*16 f32 (reused for both activations)
// [3584000  , 3684000) flags   100000 * u8  (edge-is-unique)
#define OFF_DEGC 2000000
#define OFF_DEGV 2016000
#define OFF_Y    2048000
#define OFF_X    2816000
#define OFF_FLAG 3584000
#define ZERO_BYTES 2816000   // bitmap + deg_c + deg_v + y in one memset

// Dedupe edges (adjacency has SET semantics: duplicates collapse) and count
// unique-neighbor degrees for both endpoints.
__global__ void dedup_deg_kernel(const int* __restrict__ e0,
                                 const int* __restrict__ e1,
                                 unsigned int* __restrict__ bitmap,
                                 int* __restrict__ deg_c,
                                 int* __restrict__ deg_v,
                                 unsigned char* __restrict__ flags) {
    int i = blockIdx.x * blockDim.x + threadIdx.x;
    if (i >= N_EDGES) return;
    int c = e0[i];
    int v = e1[i];                       // in [0, N_CONS) per reference randint
    unsigned int bit  = (unsigned int)c * 4000u + (unsigned int)v;
    unsigned int word = bit >> 5;
    unsigned int mask = 1u << (int)(bit & 31u);
    unsigned int old  = atomicOr(&bitmap[word], mask);
    int isnew = (old & mask) ? 0 : 1;
    flags[i] = (unsigned char)isnew;
    if (isnew) {
        atomicAdd(&deg_c[c], 1);
        atomicAdd(&deg_v[v], 1);
    }
}

// Input embeddings: rows [0,4000) = cons_x @ W_cons + b_cons (IN_CONS=1),
// rows [4000,12000) = var_x @ W_var + b_var (IN_VAR=9).
__global__ void embed_kernel(const float* __restrict__ cons_x,
                             const float* __restrict__ var_x,
                             const float* __restrict__ W_var,
                             const float* __restrict__ b_var,
                             const float* __restrict__ W_cons,
                             const float* __restrict__ b_cons,
                             float* __restrict__ x0) {
    int t = blockIdx.x * blockDim.x + threadIdx.x;
    if (t >= N_TOTAL * HID) return;
    int r = t >> 4;
    int h = t & 15;
    float val;
    if (r < N_CONS) {
        val = cons_x[r] * W_cons[h] + b_cons[h];
    } else {
        int rv = r - N_CONS;
        val = b_var[h];
        #pragma unroll
        for (int k = 0; k < 9; ++k)
            val += var_x[rv * 9 + k] * W_var[k * HID + h];
    }
    x0[t] = val;
}

// Edge-parallel symmetric aggregation over UNIQUE edges: y += A @ x
// (un-normalized; 1/deg folded into the consumer).
__global__ void agg_kernel(const int* __restrict__ e0,
                           const int* __restrict__ e1,
                           const unsigned char* __restrict__ flags,
                           const float* __restrict__ x,
                           float* __restrict__ y) {
    int t = blockIdx.x * blockDim.x + threadIdx.x;
    if (t >= N_EDGES * HID) return;
    int e = t >> 4;
    int h = t & 15;
    if (!flags[e]) return;
    int c = e0[e];
    int v = e1[e] + N_CONS;
    atomicAdd(&y[v * HID + h], x[c * HID + h]);
    atomicAdd(&y[c * HID + h], x[v * HID + h]);
}

// x_out = relu((y/deg) @ W + b)   (reads y, writes x in place — no overlap)
__global__ void lin_relu_kernel(const float* __restrict__ y,
                                const int* __restrict__ deg_c,
                                const int* __restrict__ deg_v,
                                const float* __restrict__ W,
                                const float* __restrict__ b,
                                float* __restrict__ xo) {
    int t = blockIdx.x * blockDim.x + threadIdx.x;
    if (t >= N_TOTAL * HID) return;
    int r = t >> 4;
    int ho = t & 15;
    int d = (r < N_CONS) ? deg_c[r] : deg_v[r - N_CONS];
    float inv = 1.0f / (float)max(d, 1);
    float acc = 0.0f;
    #pragma unroll
    for (int h = 0; h < HID; ++h)
        acc += y[r * HID + h] * W[h * HID + ho];
    acc = acc * inv + b[ho];
    xo[t] = fmaxf(acc, 0.0f);
}

// out = mean over rows of ((y/deg) @ W2 + b2); block-level LDS reduction then
// one atomicAdd per (block, h) — 750 atomics per output element.
__global__ void lin2_mean_kernel(const float* __restrict__ y2,
                                 const int* __restrict__ deg_c,
                                 const int* __restrict__ deg_v,
                                 const float* __restrict__ W,
                                 const float* __restrict__ b,
                                 float* __restrict__ out) {
    __shared__ float s[16][17];
    int t = blockIdx.x * blockDim.x + threadIdx.x;
    int r = t >> 4;
    int ho = t & 15;
    int rl = threadIdx.x >> 4;   // local row 0..15
    float val = 0.0f;
    if (r < N_TOTAL) {
        int d = (r < N_CONS) ? deg_c[r] : deg_v[r - N_CONS];
        float inv = 1.0f / (float)max(d, 1);
        float acc = 0.0f;
        #pragma unroll
        for (int h = 0; h < HID; ++h)
            acc += y2[r * HID + h] * W[h * HID + ho];
        val = acc * inv + b[ho];
    }
    s[rl][ho] = val;
    __syncthreads();
    if (threadIdx.x < 16) {
        float sum = 0.0f;
        #pragma unroll
        for (int i = 0; i < 16; ++i)
            sum += s[i][threadIdx.x];
        atomicAdd(&out[threadIdx.x], sum * (1.0f / (float)N_TOTAL));
    }
}

extern "C" void kernel_launch(void* const* d_in, const int* in_sizes, int n_in,
                              void* d_out, int out_size, void* d_ws, size_t ws_size,
                              hipStream_t stream) {
    const float* cons_x = (const float*)d_in[0];
    const float* var_x  = (const float*)d_in[1];
    const int*   ei     = (const int*)d_in[2];   // harness stages integers as int32
    // d_in[3] = edge_attr (unused by the reference)
    const float* W_var  = (const float*)d_in[4];
    const float* b_var  = (const float*)d_in[5];
    const float* W_cons = (const float*)d_in[6];
    const float* b_cons = (const float*)d_in[7];
    const float* W1     = (const float*)d_in[8];
    const float* b1     = (const float*)d_in[9];
    const float* W2     = (const float*)d_in[10];
    const float* b2     = (const float*)d_in[11];
    float* out = (float*)d_out;

    char* ws = (char*)d_ws;
    unsigned int*  bitmap = (unsigned int*)ws;
    int*           deg_c  = (int*)(ws + OFF_DEGC);
    int*           deg_v  = (int*)(ws + OFF_DEGV);
    float*         y      = (float*)(ws + OFF_Y);
    float*         x      = (float*)(ws + OFF_X);
    unsigned char* flags  = (unsigned char*)(ws + OFF_FLAG);

    const int* e0 = ei;             // row 0: cons indices
    const int* e1 = ei + N_EDGES;   // row 1: var indices (also in [0,4000))

    // zero bitmap + degrees + y (one contiguous memset) and the output accum
    hipMemsetAsync(d_ws, 0, ZERO_BYTES, stream);
    hipMemsetAsync(d_out, 0, HID * sizeof(float), stream);

    dedup_deg_kernel<<<(N_EDGES + 255) / 256, 256, 0, stream>>>(
        e0, e1, bitmap, deg_c, deg_v, flags);

    embed_kernel<<<(N_TOTAL * HID + 255) / 256, 256, 0, stream>>>(
        cons_x, var_x, W_var, b_var, W_cons, b_cons, x);

    agg_kernel<<<(N_EDGES * HID + 255) / 256, 256, 0, stream>>>(
        e0, e1, flags, x, y);

    lin_relu_kernel<<<(N_TOTAL * HID + 255) / 256, 256, 0, stream>>>(
        y, deg_c, deg_v, W1, b1, x);          // x overwritten in place (reads only y)

    hipMemsetAsync(ws + OFF_Y, 0, N_TOTAL * HID * sizeof(float), stream);  // re-zero y

    agg_kernel<<<(N_EDGES * HID + 255) / 256, 256, 0, stream>>>(
        e0, e1, flags, x, y);

    lin2_mean_kernel<<<(N_TOTAL * HID + 255) / 256, 256, 0, stream>>>(
        y, deg_c, deg_v, W2, b2, out);
}